// Round 3
// baseline (570.561 us; speedup 1.0000x reference)
//
#include <hip/hip_runtime.h>
#include <hip/hip_bf16.h>

#define DIM 768
#define HEADS 12
#define HD 64
#define HIDDEN 3072
#define SEQ 1024
#define NB 8
#define M_TOK (NB * SEQ)   // 8192 tokens
#define C3 (3 * DIM)       // 2304

typedef __attribute__((ext_vector_type(8))) short short8;    // 8 x bf16 (4 VGPRs)
typedef __attribute__((ext_vector_type(4))) short shortx4;   // 4 x bf16 (8B)
typedef __attribute__((ext_vector_type(4))) float floatx4;   // MFMA accum

__device__ __forceinline__ void gload_lds16(const void* g, void* l) {
  __builtin_amdgcn_global_load_lds((const __attribute__((address_space(1))) void*)g,
                                   (__attribute__((address_space(3))) void*)l, 16, 0, 0);
}

__device__ __forceinline__ unsigned short bf16b(float f) {
  __hip_bfloat16 h = __float2bfloat16(f);
  return *(unsigned short*)&h;
}

// ---------------------------------------------------------------------------
// Weight transpose + f32->bf16 cast: w[K][N] -> wt[N][K]
// ---------------------------------------------------------------------------
__global__ __launch_bounds__(256) void transpose_cast(
    const float* __restrict__ w, __hip_bfloat16* __restrict__ wt, int K, int N) {
  __shared__ float tile[32][33];
  const int tx = threadIdx.x & 31, ty = threadIdx.x >> 5;
  const int n0 = blockIdx.x * 32, k0 = blockIdx.y * 32;
#pragma unroll
  for (int i = 0; i < 32; i += 8)
    tile[ty + i][tx] = w[(size_t)(k0 + ty + i) * N + n0 + tx];
  __syncthreads();
#pragma unroll
  for (int i = 0; i < 32; i += 8)
    wt[(size_t)(n0 + ty + i) * K + k0 + tx] = __float2bfloat16(tile[tx][ty + i]);
}

// ---------------------------------------------------------------------------
// LayerNorm (f32 in) -> bf16 out.  One block per row of 768.
// ---------------------------------------------------------------------------
__global__ __launch_bounds__(256) void ln_kernel(
    const float* __restrict__ x, const float* __restrict__ gw,
    const float* __restrict__ bw, __hip_bfloat16* __restrict__ outp) {
  const int row = blockIdx.x;
  const int t = threadIdx.x;
  const float* xr = x + (size_t)row * DIM;
  float v0 = xr[t], v1 = xr[t + 256], v2 = xr[t + 512];
  float s = v0 + v1 + v2;
  float sq = v0 * v0 + v1 * v1 + v2 * v2;
#pragma unroll
  for (int m = 1; m < 64; m <<= 1) {
    s += __shfl_xor(s, m);
    sq += __shfl_xor(sq, m);
  }
  __shared__ float ss[4], ssq[4];
  const int wave = t >> 6, lane = t & 63;
  if (lane == 0) { ss[wave] = s; ssq[wave] = sq; }
  __syncthreads();
  s = ss[0] + ss[1] + ss[2] + ss[3];
  sq = ssq[0] + ssq[1] + ssq[2] + ssq[3];
  const float mean = s * (1.f / 768.f);
  const float var = sq * (1.f / 768.f) - mean * mean;
  const float rstd = rsqrtf(var + 1e-5f);
  __hip_bfloat16* orow = outp + (size_t)row * DIM;
  orow[t]       = __float2bfloat16((v0 - mean) * rstd * gw[t]       + bw[t]);
  orow[t + 256] = __float2bfloat16((v1 - mean) * rstd * gw[t + 256] + bw[t + 256]);
  orow[t + 512] = __float2bfloat16((v2 - mean) * rstd * gw[t + 512] + bw[t + 512]);
}

// ---------------------------------------------------------------------------
// GEMM: C[M][N] = A[M][K] (bf16) @ BT[N][K]^T (bf16)  [+bias][gelu][+resid]
// 128x128 tile, BK=64, 4 waves (2x2), 4x4 16x16x32 fragments per wave.
// OUTMODE: 0 = f32 out, 1 = bf16 out, 2 = scatter to Qc/Kc[B,H,S,64]+Vt[B,H,64,S]
// ---------------------------------------------------------------------------
template <int BIAS, int GELU, int RES, int OUTMODE>
__global__ __launch_bounds__(256) void gemm_bt(
    const __hip_bfloat16* __restrict__ A, const __hip_bfloat16* __restrict__ BT,
    const float* __restrict__ bias, const float* __restrict__ resid,
    void* __restrict__ Cout,
    __hip_bfloat16* __restrict__ Qc, __hip_bfloat16* __restrict__ Kc,
    __hip_bfloat16* __restrict__ Vt,
    int M, int N, int K) {
  __shared__ __align__(16) __hip_bfloat16 As[128 * 64];
  __shared__ __align__(16) __hip_bfloat16 Bs[128 * 64];
  const int tid = threadIdx.x;
  const int wave = tid >> 6, lane = tid & 63;
  const int g = lane >> 4, fr = lane & 15;

  // bijective XCD swizzle (nwg % 8 == 0 for all our launches)
  const int gx = gridDim.x;
  const int nwg = gx * gridDim.y;
  int bi = blockIdx.y * gx + blockIdx.x;
  bi = (bi & 7) * (nwg >> 3) + (bi >> 3);
  const int m0 = (bi / gx) * 128, n0 = (bi % gx) * 128;
  const int wm = (wave >> 1) * 64, wn = (wave & 1) * 64;

  floatx4 acc[4][4];
  const floatx4 zero = {0.f, 0.f, 0.f, 0.f};
#pragma unroll
  for (int m = 0; m < 4; ++m)
#pragma unroll
    for (int n = 0; n < 4; ++n) acc[m][n] = zero;

  for (int kt = 0; kt < K; kt += 64) {
#pragma unroll
    for (int i = 0; i < 4; ++i) {
      const int li = i * 256 + tid;
      const int row = li >> 3, k8 = (li & 7) << 3;
      gload_lds16(A + (size_t)(m0 + row) * K + kt + k8, As + li * 8);
      gload_lds16(BT + (size_t)(n0 + row) * K + kt + k8, Bs + li * 8);
    }
    __syncthreads();
#pragma unroll
    for (int kk = 0; kk < 64; kk += 32) {
      short8 af[4], bfr[4];
#pragma unroll
      for (int m = 0; m < 4; ++m)
        af[m] = *(const short8*)(As + (wm + m * 16 + fr) * 64 + kk + g * 8);
#pragma unroll
      for (int n = 0; n < 4; ++n)
        bfr[n] = *(const short8*)(Bs + (wn + n * 16 + fr) * 64 + kk + g * 8);
#pragma unroll
      for (int m = 0; m < 4; ++m)
#pragma unroll
        for (int n = 0; n < 4; ++n)
          acc[m][n] = __builtin_amdgcn_mfma_f32_16x16x32_bf16(af[m], bfr[n], acc[m][n], 0, 0, 0);
    }
    __syncthreads();
  }

#pragma unroll
  for (int m = 0; m < 4; ++m) {
    const int row = m0 + wm + m * 16 + g * 4;
#pragma unroll
    for (int n = 0; n < 4; ++n) {
      const int col = n0 + wn + n * 16 + fr;
      if (OUTMODE == 2) {
        // scatter into attention-friendly layouts
        const int part = (col >= 1536) ? 2 : (col >= 768 ? 1 : 0);
        const int cc = col - part * 768;
        const int h = cc >> 6, d = cc & 63;
        const int b = row >> 10, s = row & 1023;  // row%4==0 so s..s+3 same b
        const size_t hb = (size_t)b * HEADS + h;
        if (part == 2) {
          shortx4 pk;
#pragma unroll
          for (int r = 0; r < 4; ++r) pk[r] = (short)bf16b(acc[m][n][r]);
          *(shortx4*)(Vt + (hb * HD + d) * SEQ + s) = pk;
        } else {
          __hip_bfloat16* dst = (part ? Kc : Qc) + (hb * SEQ + s) * HD + d;
#pragma unroll
          for (int r = 0; r < 4; ++r) dst[(size_t)r * HD] = __float2bfloat16(acc[m][n][r]);
        }
      } else {
        const float bv = BIAS ? bias[col] : 0.f;
#pragma unroll
        for (int r = 0; r < 4; ++r) {
          float c = acc[m][n][r] + bv;
          if (GELU) c = 0.5f * c * (1.f + erff(c * 0.70710678118f));
          const size_t off = (size_t)(row + r) * N + col;
          if (RES) c += resid[off];
          if (OUTMODE == 1) ((__hip_bfloat16*)Cout)[off] = __float2bfloat16(c);
          else              ((float*)Cout)[off] = c;
        }
      }
    }
  }
}

// ---------------------------------------------------------------------------
// Flash attention on Qc/Kc [BH,S,64] + Vt [BH,64,S].
// grid 1536 blocks (16 q-tiles x 96 heads), 4 waves, 16 q-rows/wave, KV step 64.
// P transposed through XOR-swizzled per-wave LDS ((row&7)<<4, G4 pattern).
// ---------------------------------------------------------------------------
__global__ __launch_bounds__(256) void attn_kernel(
    const __hip_bfloat16* __restrict__ Qc, const __hip_bfloat16* __restrict__ Kc,
    const __hip_bfloat16* __restrict__ Vt, __hip_bfloat16* __restrict__ outp) {
  const int wave = threadIdx.x >> 6, lane = threadIdx.x & 63;
  const int g = lane >> 4, fr = lane & 15;

  // bijective XCD swizzle: 1536 blocks, each XCD gets 12 whole heads
  int bi = blockIdx.y * gridDim.x + blockIdx.x;
  bi = (bi & 7) * 192 + (bi >> 3);
  const int qt = bi & 15, bh = bi >> 4;
  const int b = bh / HEADS, h = bh % HEADS;
  const int q0 = qt * 64 + wave * 16;

  const __hip_bfloat16* qp = Qc + ((size_t)bh * SEQ + q0 + fr) * HD;
  const short8 qf0 = *(const short8*)(qp + g * 8);
  const short8 qf1 = *(const short8*)(qp + 32 + g * 8);

  const __hip_bfloat16* kbase = Kc + (size_t)bh * SEQ * HD;
  const __hip_bfloat16* vbase = Vt + (size_t)bh * HD * SEQ;

  __shared__ __align__(16) __hip_bfloat16 P[4][16 * 64];
  char* const pw = (char*)P[wave];

  float m_r[4], l_r[4];
  floatx4 acc_o[4];
  const floatx4 zero = {0.f, 0.f, 0.f, 0.f};
#pragma unroll
  for (int r = 0; r < 4; ++r) { m_r[r] = -1e30f; l_r[r] = 0.f; }
#pragma unroll
  for (int n = 0; n < 4; ++n) acc_o[n] = zero;

  for (int kt = 0; kt < SEQ; kt += 64) {
    floatx4 sa[4];
#pragma unroll
    for (int kb = 0; kb < 4; ++kb) {
      const __hip_bfloat16* kp = kbase + (size_t)(kt + kb * 16 + fr) * HD;
      const short8 k0 = *(const short8*)(kp + g * 8);
      const short8 k1 = *(const short8*)(kp + 32 + g * 8);
      sa[kb] = __builtin_amdgcn_mfma_f32_16x16x32_bf16(qf0, k0, zero, 0, 0, 0);
      sa[kb] = __builtin_amdgcn_mfma_f32_16x16x32_bf16(qf1, k1, sa[kb], 0, 0, 0);
    }
#pragma unroll
    for (int r = 0; r < 4; ++r) {
      const float s0 = sa[0][r] * 0.125f, s1 = sa[1][r] * 0.125f;
      const float s2 = sa[2][r] * 0.125f, s3 = sa[3][r] * 0.125f;
      float mx = fmaxf(fmaxf(s0, s1), fmaxf(s2, s3));
      mx = fmaxf(mx, __shfl_xor(mx, 1));
      mx = fmaxf(mx, __shfl_xor(mx, 2));
      mx = fmaxf(mx, __shfl_xor(mx, 4));
      mx = fmaxf(mx, __shfl_xor(mx, 8));
      const float mn = fmaxf(m_r[r], mx);
      const float alpha = __expf(m_r[r] - mn);
      const float p0 = __expf(s0 - mn), p1 = __expf(s1 - mn);
      const float p2 = __expf(s2 - mn), p3 = __expf(s3 - mn);
      float rs = (p0 + p1) + (p2 + p3);
      rs += __shfl_xor(rs, 1);
      rs += __shfl_xor(rs, 2);
      rs += __shfl_xor(rs, 4);
      rs += __shfl_xor(rs, 8);
      l_r[r] = l_r[r] * alpha + rs;
      m_r[r] = mn;
#pragma unroll
      for (int n = 0; n < 4; ++n) acc_o[n][r] *= alpha;
      const int qrow = g * 4 + r;
      const int swz = (qrow & 7) << 4;
      char* prow = pw + qrow * 128;
      *(__hip_bfloat16*)(prow + (((fr * 2)      ) ^ swz)) = __float2bfloat16(p0);
      *(__hip_bfloat16*)(prow + (((fr * 2) +  32) ^ swz)) = __float2bfloat16(p1);
      *(__hip_bfloat16*)(prow + (((fr * 2) +  64) ^ swz)) = __float2bfloat16(p2);
      *(__hip_bfloat16*)(prow + (((fr * 2) +  96) ^ swz)) = __float2bfloat16(p3);
    }
    const int rsw = (fr & 7) << 4;
    const short8 pf0 = *(const short8*)(pw + fr * 128 + ((g * 16) ^ rsw));
    const short8 pf1 = *(const short8*)(pw + fr * 128 + ((64 + g * 16) ^ rsw));
#pragma unroll
    for (int n = 0; n < 4; ++n) {
      const __hip_bfloat16* vp = vbase + (size_t)(n * 16 + fr) * SEQ + kt;
      const short8 v0 = *(const short8*)(vp + g * 8);
      const short8 v1 = *(const short8*)(vp + 32 + g * 8);
      acc_o[n] = __builtin_amdgcn_mfma_f32_16x16x32_bf16(pf0, v0, acc_o[n], 0, 0, 0);
      acc_o[n] = __builtin_amdgcn_mfma_f32_16x16x32_bf16(pf1, v1, acc_o[n], 0, 0, 0);
    }
  }

  __hip_bfloat16* op = outp + (size_t)(b * SEQ + q0) * DIM + h * HD;
#pragma unroll
  for (int n = 0; n < 4; ++n)
#pragma unroll
    for (int r = 0; r < 4; ++r)
      op[(size_t)(g * 4 + r) * DIM + n * 16 + fr] =
          __float2bfloat16(acc_o[n][r] / l_r[r]);
}

// ---------------------------------------------------------------------------
extern "C" void kernel_launch(void* const* d_in, const int* in_sizes, int n_in,
                              void* d_out, int out_size, void* d_ws, size_t ws_size,
                              hipStream_t stream) {
  (void)in_sizes; (void)n_in; (void)out_size; (void)ws_size;
  const float* x      = (const float*)d_in[0];
  const float* ln1_g  = (const float*)d_in[1];
  const float* ln1_b  = (const float*)d_in[2];
  const float* w_qkv  = (const float*)d_in[3];
  const float* w_proj = (const float*)d_in[4];
  const float* b_proj = (const float*)d_in[5];
  const float* ln2_g  = (const float*)d_in[6];
  const float* ln2_b  = (const float*)d_in[7];
  const float* w_fc1  = (const float*)d_in[8];
  const float* b_fc1  = (const float*)d_in[9];
  const float* w_fc2  = (const float*)d_in[10];
  const float* b_fc2  = (const float*)d_in[11];
  float* outp = (float*)d_out;

  char* ws = (char*)d_ws;
  size_t off = 0;
  auto alloc = [&](size_t bytes) -> void* {
    void* p = ws + off;
    off += (bytes + 255) & ~(size_t)255;
    return p;
  };
  __hip_bfloat16* h1     = (__hip_bfloat16*)alloc((size_t)M_TOK * DIM * 2);
  __hip_bfloat16* Qc     = (__hip_bfloat16*)alloc((size_t)M_TOK * DIM * 2);
  __hip_bfloat16* Kc     = (__hip_bfloat16*)alloc((size_t)M_TOK * DIM * 2);
  __hip_bfloat16* Vt     = (__hip_bfloat16*)alloc((size_t)M_TOK * DIM * 2);
  __hip_bfloat16* att    = (__hip_bfloat16*)alloc((size_t)M_TOK * DIM * 2);
  __hip_bfloat16* h2     = (__hip_bfloat16*)alloc((size_t)M_TOK * DIM * 2);
  __hip_bfloat16* act    = (__hip_bfloat16*)alloc((size_t)M_TOK * HIDDEN * 2);
  __hip_bfloat16* wqkvT  = (__hip_bfloat16*)alloc((size_t)C3 * DIM * 2);
  __hip_bfloat16* wprojT = (__hip_bfloat16*)alloc((size_t)DIM * DIM * 2);
  __hip_bfloat16* wfc1T  = (__hip_bfloat16*)alloc((size_t)HIDDEN * DIM * 2);
  __hip_bfloat16* wfc2T  = (__hip_bfloat16*)alloc((size_t)DIM * HIDDEN * 2);
  float* x_mid = outp;  // mid-residual lives in d_out (fully rewritten each call)

  transpose_cast<<<dim3(C3 / 32, DIM / 32), 256, 0, stream>>>(w_qkv, wqkvT, DIM, C3);
  transpose_cast<<<dim3(DIM / 32, DIM / 32), 256, 0, stream>>>(w_proj, wprojT, DIM, DIM);
  transpose_cast<<<dim3(HIDDEN / 32, DIM / 32), 256, 0, stream>>>(w_fc1, wfc1T, DIM, HIDDEN);
  transpose_cast<<<dim3(DIM / 32, HIDDEN / 32), 256, 0, stream>>>(w_fc2, wfc2T, HIDDEN, DIM);

  ln_kernel<<<M_TOK, 256, 0, stream>>>(x, ln1_g, ln1_b, h1);
  gemm_bt<0, 0, 0, 2><<<dim3(C3 / 128, M_TOK / 128), 256, 0, stream>>>(
      h1, wqkvT, nullptr, nullptr, nullptr, Qc, Kc, Vt, M_TOK, C3, DIM);
  attn_kernel<<<dim3(SEQ / 64, NB * HEADS), 256, 0, stream>>>(Qc, Kc, Vt, att);
  gemm_bt<1, 0, 1, 0><<<dim3(DIM / 128, M_TOK / 128), 256, 0, stream>>>(
      att, wprojT, b_proj, x, x_mid, nullptr, nullptr, nullptr, M_TOK, DIM, DIM);
  ln_kernel<<<M_TOK, 256, 0, stream>>>(x_mid, ln2_g, ln2_b, h2);
  gemm_bt<1, 1, 0, 1><<<dim3(HIDDEN / 128, M_TOK / 128), 256, 0, stream>>>(
      h2, wfc1T, b_fc1, nullptr, act, nullptr, nullptr, nullptr, M_TOK, HIDDEN, DIM);
  gemm_bt<1, 0, 1, 0><<<dim3(DIM / 128, M_TOK / 128), 256, 0, stream>>>(
      act, wfc2T, b_fc2, x_mid, outp, nullptr, nullptr, nullptr, M_TOK, DIM, HIDDEN);
}